// Round 1
// baseline (118.531 us; speedup 1.0000x reference)
//
#include <hip/hip_runtime.h>
#include <hip/hip_bf16.h>

typedef __bf16 bf16_t;
typedef __bf16 bf16x4 __attribute__((ext_vector_type(4)));
typedef __bf16 bf16x8 __attribute__((ext_vector_type(8)));
typedef float f32x4 __attribute__((ext_vector_type(4)));

#define M_TOT 8192
#define N_TOT 512
#define K_TOT 2048
#define E_TOT 512
#define NSEG  16          // K segments of 128

__device__ __forceinline__ bf16x8 zero8() {
    bf16x8 v;
#pragma unroll
    for (int i = 0; i < 8; ++i) v[i] = (bf16_t)0.0f;
    return v;
}

// ---------------------------------------------------------------------------
// prep4 (unchanged; correctness-proven):
//  blocks [0,256):   LDS-tiled transpose W2[k][n] -> W2t[n][k] bf16
//  blocks [256,288): zb[m][0..8)=cos(theta[q])*cos(x[m,q]) (RX collapse:
//                    |a2|^2-|b2|^2 = cos(theta)*cos(x)); zb[m][8]=1; rest 0
//  blocks [288,296): W1p: permuted W1 rows + bias so h-MFMA C-output lands
//    exactly in main-MFMA A-fragment layout.
//    Row d=(c*2+p)*16+rr holds f = c*32+(rr>>2)*8+p*4+(rr&3).
// ---------------------------------------------------------------------------
__global__ __launch_bounds__(256)
void prep4_kernel(const float* __restrict__ x,
                  const float* __restrict__ theta,
                  const float* __restrict__ W1,
                  const float* __restrict__ b1,
                  const float* __restrict__ W2,
                  bf16_t* __restrict__ W2t,
                  bf16_t* __restrict__ zb,
                  bf16_t* __restrict__ W1p)
{
    const int b = blockIdx.x;
    if (b < 256) {
        __shared__ bf16_t T[64][66];
        const int k0 = (b >> 3) * 64;
        const int n0 = (b & 7) * 64;
        const int kl = threadIdx.x >> 4;
        const int n4 = threadIdx.x & 15;
#pragma unroll
        for (int i = 0; i < 4; ++i) {
            int k = kl + i * 16;
            float4 v = *(const float4*)(W2 + (size_t)(k0 + k) * N_TOT + n0 + n4 * 4);
            T[n4 * 4 + 0][k] = (bf16_t)v.x;
            T[n4 * 4 + 1][k] = (bf16_t)v.y;
            T[n4 * 4 + 2][k] = (bf16_t)v.z;
            T[n4 * 4 + 3][k] = (bf16_t)v.w;
        }
        __syncthreads();
        const int nl = threadIdx.x >> 4;
        const int k4 = threadIdx.x & 15;
#pragma unroll
        for (int i = 0; i < 4; ++i) {
            int n = nl + i * 16;
            bf16x4 v;
            v[0] = T[n][k4 * 4 + 0];
            v[1] = T[n][k4 * 4 + 1];
            v[2] = T[n][k4 * 4 + 2];
            v[3] = T[n][k4 * 4 + 3];
            *(bf16x4*)(W2t + (size_t)(n0 + n) * K_TOT + k0 + k4 * 4) = v;
        }
    } else if (b < 288) {
        const int m = (b - 256) * 256 + threadIdx.x;
        float4 x0 = *(const float4*)(x + (size_t)m * E_TOT);
        float4 x1 = *(const float4*)(x + (size_t)m * E_TOT + 4);
        float xs[8] = {x0.x, x0.y, x0.z, x0.w, x1.x, x1.y, x1.z, x1.w};
        bf16x8 lo;
#pragma unroll
        for (int q = 0; q < 8; ++q)
            lo[q] = (bf16_t)(__builtin_cosf(theta[q]) * __builtin_cosf(xs[q]));
        bf16x8 hi = zero8();
        hi[0] = (bf16_t)1.0f;                  // bias lane at k=8
        *(bf16x8*)(zb + (size_t)m * 16)     = lo;
        *(bf16x8*)(zb + (size_t)m * 16 + 8) = hi;
    } else {
        const int d  = (b - 288) * 256 + threadIdx.x;    // 0..2047
        const int c  = d >> 5;
        const int dd = d & 31;
        const int p  = dd >> 4;
        const int rr = dd & 15;
        const int f  = c * 32 + ((rr >> 2) << 3) + (p << 2) + (rr & 3);
        bf16x8 lo;
#pragma unroll
        for (int q = 0; q < 8; ++q)
            lo[q] = (bf16_t)W1[(size_t)q * K_TOT + f];
        bf16x8 hi = zero8();
        hi[0] = (bf16_t)b1[f];                 // bias at k=8
        *(bf16x8*)(W1p + (size_t)d * 16)     = lo;
        *(bf16x8*)(W1p + (size_t)d * 16 + 8) = hi;
    }
}

// ---------------------------------------------------------------------------
// helpers (256-thread block, block tile 128m x 64n, segment BK=128)
// ---------------------------------------------------------------------------
// B segment: 64n x 128k bf16 = 16KB, stored as two 64x64 k-tiles.
// Within a k-tile, LDS slot `seg` of row n holds global k-seg g = seg^(n&7).
__device__ __forceinline__ void load_B(const bf16_t* __restrict__ W2t, int n_base,
                                       int k0, int t, uint4 gv[4]) {
#pragma unroll
    for (int j = 0; j < 4; ++j) {
        int s    = t + j * 256;        // 0..1023
        int tile = s >> 9;             // 0..1 (which 64-k tile)
        int n    = (s >> 3) & 63;
        int g    = (s & 7) ^ (n & 7);
        gv[j] = *(const uint4*)(W2t + (size_t)(n_base + n) * K_TOT
                                + k0 + tile * 64 + g * 8);
    }
}
__device__ __forceinline__ void write_B(bf16_t* Bb, int t, const uint4 gv[4]) {
#pragma unroll
    for (int j = 0; j < 4; ++j) {
        int s    = t + j * 256;
        int tile = s >> 9;
        int n    = (s >> 3) & 63;
        int seg  = s & 7;
        *(uint4*)(Bb + tile * 4096 + n * 64 + seg * 8) = gv[j];
    }
}

// W1p frags for a FULL 128-k segment (2 tiles x 2 chunks x 2 perm-halves);
// lanes lq<2 real. Loaded a whole segment ahead of consumption so the L2
// latency never sits on the h-MFMA critical path.
__device__ __forceinline__ void load_wf_seg(const bf16_t* __restrict__ W1p, int s,
                                            int l15, int lq, bf16x8 wfs[2][4]) {
#pragma unroll
    for (int tt = 0; tt < 2; ++tt) {
        const int base = s * 8 + tt * 4;          // == ((s*128+tt*64)>>5)*2
#pragma unroll
        for (int i = 0; i < 4; ++i) {
            wfs[tt][i] = zero8();
            if (lq < 2)
                wfs[tt][i] = *(const bf16x8*)(W1p + (size_t)((base + i) * 16 + l15) * 16 + lq * 8);
        }
    }
}

// h-stage for one full segment: register-only (wfs + zfrag -> af).
// Independent of LDS / B-tiles, so it pipelines a segment ahead of the mains.
__device__ __forceinline__ void compute_h(const bf16x8 wfs[2][4],
                                          const bf16x8 zfrag[2],
                                          bf16x8 af[2][2][2]) {
#pragma unroll
    for (int tt = 0; tt < 2; ++tt)
#pragma unroll
        for (int mt = 0; mt < 2; ++mt)
#pragma unroll
            for (int c = 0; c < 2; ++c) {
                f32x4 h0 = (f32x4){0.f, 0.f, 0.f, 0.f};
                f32x4 h1 = (f32x4){0.f, 0.f, 0.f, 0.f};
                h0 = __builtin_amdgcn_mfma_f32_16x16x32_bf16(wfs[tt][c * 2 + 0], zfrag[mt], h0, 0, 0, 0);
                h1 = __builtin_amdgcn_mfma_f32_16x16x32_bf16(wfs[tt][c * 2 + 1], zfrag[mt], h1, 0, 0, 0);
                bf16x8 a;
#pragma unroll
                for (int r = 0; r < 4; ++r) {
                    a[r]     = (bf16_t)fmaxf(h0[r], 0.f);
                    a[r + 4] = (bf16_t)fmaxf(h1[r], 0.f);
                }
                af[tt][mt][c] = a;
            }
}

// main-stage for one full segment: 16 ds_read_b128 + 32 main MFMAs.
// Same MFMA issue order per acc register as the previous version
// (tt outer, c outer of mt/nt) -> bit-identical numerics.
__device__ __forceinline__ void compute_main(const bf16_t* Bb,
                                             const bf16x8 af[2][2][2],
                                             int l15, int lq, f32x4 acc[2][4]) {
#pragma unroll
    for (int tt = 0; tt < 2; ++tt) {
        bf16x8 bfr[2][4];
#pragma unroll
        for (int c = 0; c < 2; ++c)
#pragma unroll
            for (int nt = 0; nt < 4; ++nt) {
                int r  = nt * 16 + l15;
                int sm = (c * 4 + lq) ^ (r & 7);
                bfr[c][nt] = *(const bf16x8*)(Bb + tt * 4096 + r * 64 + sm * 8);
            }
#pragma unroll
        for (int c = 0; c < 2; ++c)
#pragma unroll
            for (int mt = 0; mt < 2; ++mt)
#pragma unroll
                for (int nt = 0; nt < 4; ++nt)
                    acc[mt][nt] = __builtin_amdgcn_mfma_f32_16x16x32_bf16(
                        af[tt][mt][c], bfr[c][nt], acc[mt][nt], 0, 0, 0);
    }
}

// one segment step of the software pipeline:
//   barrier (publish buf[cur]) ; issue B+wf loads for s+1 ;
//   mains(s) under setprio(1) ; h(s+1) ; write_B(s+1)
// af double-buffered (af_cur read, af_nxt written) so the compiler can
// freely interleave the register-only h-MFMAs with the LDS-fed mains.
__device__ __forceinline__ void seg_step(int s, const bf16_t* Bcur, bf16_t* Bnext,
                                         const bf16_t* __restrict__ W2t,
                                         const bf16_t* __restrict__ W1p,
                                         int n_base, int t, int l15, int lq,
                                         const bf16x8 zfrag[2],
                                         const bf16x8 af_cur[2][2][2],
                                         bf16x8 af_nxt[2][2][2],
                                         f32x4 acc[2][4]) {
    __syncthreads();                               // publish buf for segment s
    uint4 gv[4];
    bf16x8 wfs[2][4];
    const bool pre = (s + 1 < NSEG);
    if (pre) {
        load_B(W2t, n_base, (s + 1) * 128, t, gv);
        load_wf_seg(W1p, s + 1, l15, lq, wfs);
    }
    __builtin_amdgcn_s_setprio(1);
    compute_main(Bcur, af_cur, l15, lq, acc);
    __builtin_amdgcn_s_setprio(0);
    if (pre) {
        compute_h(wfs, zfrag, af_nxt);
        write_B(Bnext, t, gv);                     // precise vmcnt
    }
}

// ---------------------------------------------------------------------------
// Fused GEMM: out = relu(z@W1+b1) @ W2 + b2
// Block 128m x 64n, 256 thr = 4 waves (4m x 1n), wave 32m x 64n.
// Grid 512 = 2 blocks/CU -> cross-block overlap hides barrier drains.
// BK=128 segments, double-buffered (2 x 16KB LDS), ONE barrier per segment.
// Segment-level software pipeline: wf loads + h-MFMAs for segment s+1 run
// concurrently with the main MFMAs of segment s (h is B-independent).
// ---------------------------------------------------------------------------
__global__ __launch_bounds__(256, 2)
void ffq_gemm_kernel(const bf16_t* __restrict__ zb,    // [8192][16]
                     const bf16_t* __restrict__ W1p,   // [2048][16] permuted
                     const bf16_t* __restrict__ W2t,   // [512][2048]
                     const float* __restrict__ b2,
                     float* __restrict__ out)          // [8192][512]
{
    __shared__ bf16_t Blds[2][2 * 64 * 64];   // 2 bufs x (two 64x64 k-tiles)

    const int t = threadIdx.x;
    const int w = t >> 6, l = t & 63;
    const int m_base = blockIdx.y * 128;
    const int n_base = blockIdx.x * 64;
    const int wm = w;                          // 4 m-slots of 32
    const int l15 = l & 15, lq = l >> 4;

    // persistent z^T B-frags for this wave's two 16-row m-tiles
    bf16x8 zfrag[2];
#pragma unroll
    for (int mt = 0; mt < 2; ++mt) {
        zfrag[mt] = zero8();
        if (lq < 2)
            zfrag[mt] = *(const bf16x8*)(zb + (size_t)(m_base + wm * 32 + mt * 16 + l15) * 16 + lq * 8);
    }

    f32x4 acc[2][4];
#pragma unroll
    for (int mt = 0; mt < 2; ++mt)
#pragma unroll
        for (int nt = 0; nt < 4; ++nt)
            acc[mt][nt] = (f32x4){0.f, 0.f, 0.f, 0.f};

    // prologue: B segment 0 -> buf0 ; h for segment 0 -> afA
    {
        uint4 gv0[4];
        load_B(W2t, n_base, 0, t, gv0);
        write_B(Blds[0], t, gv0);
    }
    bf16x8 afA[2][2][2], afB[2][2][2];
    {
        bf16x8 wfs0[2][4];
        load_wf_seg(W1p, 0, l15, lq, wfs0);
        compute_h(wfs0, zfrag, afA);
    }

    // manually 2x-unrolled so af buffers are statically indexed (no scratch)
    for (int sp = 0; sp < NSEG; sp += 2) {
        seg_step(sp,     Blds[0], Blds[1], W2t, W1p, n_base, t, l15, lq,
                 zfrag, afA, afB, acc);
        seg_step(sp + 1, Blds[1], Blds[0], W2t, W1p, n_base, t, l15, lq,
                 zfrag, afB, afA, acc);
    }

    // ---- epilogue: C/D layout col=lane&15, row=(lane>>4)*4+r ----
#pragma unroll
    for (int nt = 0; nt < 4; ++nt) {
        int col = n_base + nt * 16 + l15;
        float bias = b2[col];
#pragma unroll
        for (int mt = 0; mt < 2; ++mt) {
#pragma unroll
            for (int r = 0; r < 4; ++r) {
                int row = m_base + wm * 32 + mt * 16 + lq * 4 + r;
                out[(size_t)row * N_TOT + col] = acc[mt][nt][r] + bias;
            }
        }
    }
}

extern "C" void kernel_launch(void* const* d_in, const int* in_sizes, int n_in,
                              void* d_out, int out_size, void* d_ws, size_t ws_size,
                              hipStream_t stream) {
    const float* x     = (const float*)d_in[0];
    const float* theta = (const float*)d_in[1];
    const float* W1    = (const float*)d_in[2];
    const float* b1    = (const float*)d_in[3];
    const float* W2    = (const float*)d_in[4];
    const float* b2    = (const float*)d_in[5];
    float* out = (float*)d_out;

    // ws: [0,2MB) W2t ; [2MB,2.25MB) zb[8192][16] ; then W1p[2048][16]
    const size_t W2T_BYTES = (size_t)N_TOT * K_TOT * sizeof(bf16_t);  // 2 MB
    const size_t ZB_BYTES  = (size_t)M_TOT * 16 * sizeof(bf16_t);     // 256 KB

    bf16_t* W2t = (bf16_t*)d_ws;
    bf16_t* zb  = (bf16_t*)((char*)d_ws + W2T_BYTES);
    bf16_t* W1p = (bf16_t*)((char*)d_ws + W2T_BYTES + ZB_BYTES);

    prep4_kernel<<<296, 256, 0, stream>>>(x, theta, W1, b1, W2, W2t, zb, W1p);

    dim3 grid(N_TOT / 64, M_TOT / 128);   // (8, 64) = 512 blocks, 2/CU
    ffq_gemm_kernel<<<grid, 256, 0, stream>>>(zb, W1p, W2t, b2, out);
}

// Round 2
// 109.316 us; speedup vs baseline: 1.0843x; 1.0843x over previous
//
#include <hip/hip_runtime.h>
#include <hip/hip_bf16.h>

typedef __bf16 bf16_t;
typedef __bf16 bf16x4 __attribute__((ext_vector_type(4)));
typedef __bf16 bf16x8 __attribute__((ext_vector_type(8)));
typedef float f32x4 __attribute__((ext_vector_type(4)));

#define M_TOT 8192
#define N_TOT 512
#define K_TOT 2048
#define E_TOT 512
#define NSEG  16          // K segments of 128

__device__ __forceinline__ bf16x8 zero8() {
    bf16x8 v;
#pragma unroll
    for (int i = 0; i < 8; ++i) v[i] = (bf16_t)0.0f;
    return v;
}

// ---------------------------------------------------------------------------
// prep4 (unchanged; correctness-proven):
//  blocks [0,256):   LDS-tiled transpose W2[k][n] -> W2t[n][k] bf16
//  blocks [256,288): zb[m][0..8)=cos(theta[q])*cos(x[m,q]) (RX collapse:
//                    |a2|^2-|b2|^2 = cos(theta)*cos(x)); zb[m][8]=1; rest 0
//  blocks [288,296): W1p: permuted W1 rows + bias so h-MFMA C-output lands
//    exactly in main-MFMA A-fragment layout.
//    Row d=(c*2+p)*16+rr holds f = c*32+(rr>>2)*8+p*4+(rr&3).
// ---------------------------------------------------------------------------
__global__ __launch_bounds__(256)
void prep4_kernel(const float* __restrict__ x,
                  const float* __restrict__ theta,
                  const float* __restrict__ W1,
                  const float* __restrict__ b1,
                  const float* __restrict__ W2,
                  bf16_t* __restrict__ W2t,
                  bf16_t* __restrict__ zb,
                  bf16_t* __restrict__ W1p)
{
    const int b = blockIdx.x;
    if (b < 256) {
        __shared__ bf16_t T[64][66];
        const int k0 = (b >> 3) * 64;
        const int n0 = (b & 7) * 64;
        const int kl = threadIdx.x >> 4;
        const int n4 = threadIdx.x & 15;
#pragma unroll
        for (int i = 0; i < 4; ++i) {
            int k = kl + i * 16;
            float4 v = *(const float4*)(W2 + (size_t)(k0 + k) * N_TOT + n0 + n4 * 4);
            T[n4 * 4 + 0][k] = (bf16_t)v.x;
            T[n4 * 4 + 1][k] = (bf16_t)v.y;
            T[n4 * 4 + 2][k] = (bf16_t)v.z;
            T[n4 * 4 + 3][k] = (bf16_t)v.w;
        }
        __syncthreads();
        const int nl = threadIdx.x >> 4;
        const int k4 = threadIdx.x & 15;
#pragma unroll
        for (int i = 0; i < 4; ++i) {
            int n = nl + i * 16;
            bf16x4 v;
            v[0] = T[n][k4 * 4 + 0];
            v[1] = T[n][k4 * 4 + 1];
            v[2] = T[n][k4 * 4 + 2];
            v[3] = T[n][k4 * 4 + 3];
            *(bf16x4*)(W2t + (size_t)(n0 + n) * K_TOT + k0 + k4 * 4) = v;
        }
    } else if (b < 288) {
        const int m = (b - 256) * 256 + threadIdx.x;
        float4 x0 = *(const float4*)(x + (size_t)m * E_TOT);
        float4 x1 = *(const float4*)(x + (size_t)m * E_TOT + 4);
        float xs[8] = {x0.x, x0.y, x0.z, x0.w, x1.x, x1.y, x1.z, x1.w};
        bf16x8 lo;
#pragma unroll
        for (int q = 0; q < 8; ++q)
            lo[q] = (bf16_t)(__builtin_cosf(theta[q]) * __builtin_cosf(xs[q]));
        bf16x8 hi = zero8();
        hi[0] = (bf16_t)1.0f;                  // bias lane at k=8
        *(bf16x8*)(zb + (size_t)m * 16)     = lo;
        *(bf16x8*)(zb + (size_t)m * 16 + 8) = hi;
    } else {
        const int d  = (b - 288) * 256 + threadIdx.x;    // 0..2047
        const int c  = d >> 5;
        const int dd = d & 31;
        const int p  = dd >> 4;
        const int rr = dd & 15;
        const int f  = c * 32 + ((rr >> 2) << 3) + (p << 2) + (rr & 3);
        bf16x8 lo;
#pragma unroll
        for (int q = 0; q < 8; ++q)
            lo[q] = (bf16_t)W1[(size_t)q * K_TOT + f];
        bf16x8 hi = zero8();
        hi[0] = (bf16_t)b1[f];                 // bias at k=8
        *(bf16x8*)(W1p + (size_t)d * 16)     = lo;
        *(bf16x8*)(W1p + (size_t)d * 16 + 8) = hi;
    }
}

// ---------------------------------------------------------------------------
// helpers (256-thread block, block tile 64m x 64n, segment BK=128)
// ---------------------------------------------------------------------------
// B segment: 64n x 128k bf16 = 16KB, stored as two 64x64 k-tiles.
// Within a k-tile, LDS slot `seg` of row n holds global k-seg g = seg^(n&7).
__device__ __forceinline__ void load_B(const bf16_t* __restrict__ W2t, int n_base,
                                       int k0, int t, uint4 gv[4]) {
#pragma unroll
    for (int j = 0; j < 4; ++j) {
        int s    = t + j * 256;        // 0..1023
        int tile = s >> 9;             // 0..1 (which 64-k tile)
        int n    = (s >> 3) & 63;
        int g    = (s & 7) ^ (n & 7);
        gv[j] = *(const uint4*)(W2t + (size_t)(n_base + n) * K_TOT
                                + k0 + tile * 64 + g * 8);
    }
}
__device__ __forceinline__ void write_B(bf16_t* Bb, int t, const uint4 gv[4]) {
#pragma unroll
    for (int j = 0; j < 4; ++j) {
        int s    = t + j * 256;
        int tile = s >> 9;
        int n    = (s >> 3) & 63;
        int seg  = s & 7;
        *(uint4*)(Bb + tile * 4096 + n * 64 + seg * 8) = gv[j];
    }
}

// W1p frags for one 64-k tile (2 chunks x 2 perm-halves); lanes lq<2 real.
__device__ __forceinline__ void load_wf(const bf16_t* __restrict__ W1p, int k0,
                                        int l15, int lq, bf16x8 wf[4]) {
#pragma unroll
    for (int i = 0; i < 4; ++i) wf[i] = zero8();
    if (lq < 2) {
        const int base = (k0 >> 5) * 2;
#pragma unroll
        for (int i = 0; i < 4; ++i)
            wf[i] = *(const bf16x8*)(W1p + (size_t)((base + i) * 16 + l15) * 16 + lq * 8);
    }
}

// one 64-k tile: B frags from LDS, h in registers (layout-matched MFMA), mains.
// wave tile 16m x 64n. MFMA order per acc[nt] over (tt,c) identical to the
// proven version -> bit-identical numerics.
__device__ __forceinline__ void compute_tile(const bf16_t* Bb, const bf16x8 wf[4],
                                             const bf16x8 zfrag,
                                             int l15, int lq,
                                             f32x4 acc[4]) {
    bf16x8 bfr[2][4];
#pragma unroll
    for (int c = 0; c < 2; ++c)
#pragma unroll
        for (int nt = 0; nt < 4; ++nt) {
            int r = nt * 16 + l15;
            int s = (c * 4 + lq) ^ (r & 7);
            bfr[c][nt] = *(const bf16x8*)(Bb + r * 64 + s * 8);
        }

    bf16x8 af[2];
#pragma unroll
    for (int c = 0; c < 2; ++c) {
        f32x4 h0 = (f32x4){0.f, 0.f, 0.f, 0.f};
        f32x4 h1 = (f32x4){0.f, 0.f, 0.f, 0.f};
        h0 = __builtin_amdgcn_mfma_f32_16x16x32_bf16(wf[c * 2 + 0], zfrag, h0, 0, 0, 0);
        h1 = __builtin_amdgcn_mfma_f32_16x16x32_bf16(wf[c * 2 + 1], zfrag, h1, 0, 0, 0);
        bf16x8 a;
#pragma unroll
        for (int r = 0; r < 4; ++r) {
            a[r]     = (bf16_t)fmaxf(h0[r], 0.f);
            a[r + 4] = (bf16_t)fmaxf(h1[r], 0.f);
        }
        af[c] = a;
    }

#pragma unroll
    for (int c = 0; c < 2; ++c)
#pragma unroll
        for (int nt = 0; nt < 4; ++nt)
            acc[nt] = __builtin_amdgcn_mfma_f32_16x16x32_bf16(
                af[c], bfr[c][nt], acc[nt], 0, 0, 0);
}

// ---------------------------------------------------------------------------
// Fused GEMM: out = relu(z@W1+b1) @ W2 + b2
// Block 64m x 64n, 256 thr = 4 waves (4m x 1n), wave 16m x 64n.
// Grid 1024 = 4 blocks/CU -> 16 waves/CU (4 waves/SIMD): TLP hides latency
// and cross-block overlap hides barrier drains (R1 showed occupancy was the
// bottleneck: MfmaUtil 20% / VALUBusy 28% / Occupancy 17.5% at 2 blocks/CU).
// BK=128 segments, double-buffered (2 x 16KB LDS), ONE barrier per segment
// (write buf[1-cur] after compute; next top-of-loop barrier publishes it).
// h entirely in registers via layout-matched h-MFMA (permuted W1p).
// ---------------------------------------------------------------------------
__global__ __launch_bounds__(256, 4)
void ffq_gemm_kernel(const bf16_t* __restrict__ zb,    // [8192][16]
                     const bf16_t* __restrict__ W1p,   // [2048][16] permuted
                     const bf16_t* __restrict__ W2t,   // [512][2048]
                     const float* __restrict__ b2,
                     float* __restrict__ out)          // [8192][512]
{
    __shared__ bf16_t Blds[2][2 * 64 * 64];   // 2 bufs x (two 64x64 k-tiles)

    const int t = threadIdx.x;
    const int w = t >> 6, l = t & 63;
    const int m_base = blockIdx.y * 64;
    const int n_base = blockIdx.x * 64;
    const int l15 = l & 15, lq = l >> 4;

    // persistent z^T B-frag for this wave's 16-row m-tile
    bf16x8 zfrag = zero8();
    if (lq < 2)
        zfrag = *(const bf16x8*)(zb + (size_t)(m_base + w * 16 + l15) * 16 + lq * 8);

    f32x4 acc[4];
#pragma unroll
    for (int nt = 0; nt < 4; ++nt)
        acc[nt] = (f32x4){0.f, 0.f, 0.f, 0.f};

    uint4 gv[4];

    // prologue: segment 0 -> buf0
    load_B(W2t, n_base, 0, t, gv);
    write_B(Blds[0], t, gv);

    for (int s = 0; s < NSEG; ++s) {
        const int cur = s & 1;
        __syncthreads();                               // publish buf[cur]
        if (s + 1 < NSEG) load_B(W2t, n_base, (s + 1) * 128, t, gv);

#pragma unroll
        for (int tt = 0; tt < 2; ++tt) {
            bf16x8 wf[4];
            load_wf(W1p, s * 128 + tt * 64, l15, lq, wf);
            compute_tile(Blds[cur] + tt * 4096, wf, zfrag, l15, lq, acc);
        }

        if (s + 1 < NSEG) write_B(Blds[1 - cur], t, gv);   // precise vmcnt
    }

    // ---- epilogue: C/D layout col=lane&15, row=(lane>>4)*4+r ----
#pragma unroll
    for (int nt = 0; nt < 4; ++nt) {
        int col = n_base + nt * 16 + l15;
        float bias = b2[col];
#pragma unroll
        for (int r = 0; r < 4; ++r) {
            int row = m_base + w * 16 + lq * 4 + r;
            out[(size_t)row * N_TOT + col] = acc[nt][r] + bias;
        }
    }
}

extern "C" void kernel_launch(void* const* d_in, const int* in_sizes, int n_in,
                              void* d_out, int out_size, void* d_ws, size_t ws_size,
                              hipStream_t stream) {
    const float* x     = (const float*)d_in[0];
    const float* theta = (const float*)d_in[1];
    const float* W1    = (const float*)d_in[2];
    const float* b1    = (const float*)d_in[3];
    const float* W2    = (const float*)d_in[4];
    const float* b2    = (const float*)d_in[5];
    float* out = (float*)d_out;

    // ws: [0,2MB) W2t ; [2MB,2.25MB) zb[8192][16] ; then W1p[2048][16]
    const size_t W2T_BYTES = (size_t)N_TOT * K_TOT * sizeof(bf16_t);  // 2 MB
    const size_t ZB_BYTES  = (size_t)M_TOT * 16 * sizeof(bf16_t);     // 256 KB

    bf16_t* W2t = (bf16_t*)d_ws;
    bf16_t* zb  = (bf16_t*)((char*)d_ws + W2T_BYTES);
    bf16_t* W1p = (bf16_t*)((char*)d_ws + W2T_BYTES + ZB_BYTES);

    prep4_kernel<<<296, 256, 0, stream>>>(x, theta, W1, b1, W2, W2t, zb, W1p);

    dim3 grid(N_TOT / 64, M_TOT / 64);    // (8, 128) = 1024 blocks, 4/CU
    ffq_gemm_kernel<<<grid, 256, 0, stream>>>(zb, W1p, W2t, b2, out);
}